// Round 8
// baseline (160.289 us; speedup 1.0000x reference)
//
#include <hip/hip_runtime.h>

typedef float f32x4 __attribute__((ext_vector_type(4)));
typedef __bf16 bf16x8 __attribute__((ext_vector_type(8)));
typedef unsigned short u16x8 __attribute__((ext_vector_type(8)));

#define D_DIM 128
#define NSPLIT 32
#define SCALE  1.2011224087864498f   // sqrt(log2(e)): both operands scaled -> acc = log2e * sim
#define LN2    0.6931471805599453f
#define E1F    2.7182818284590452f

// fp32 -> bf16 round-to-nearest-even
static __device__ __forceinline__ unsigned short f2bf(float f) {
    unsigned u = __float_as_uint(f);
    u += 0x7fffu + ((u >> 16) & 1u);
    return (unsigned short)(u >> 16);
}

// ---------------------------------------------------------------------------
// prep: normalize rows (scaled by sqrt(log2e)), store A in MFMA-fragment
// order. Fragment f = jtile*4 + kb is 1 KB: lane l holds row jtile*16+(l&15),
// k = kb*32 + (l>>4)*8 .. +7. Per-block class column-sum partials Cpart
// (plain stores, no memset needed), n0part. Block 0 zeroes scal/counter.
__global__ __launch_bounds__(256) void prep_kernel(const float* __restrict__ X,
                                                   const int* __restrict__ labels,
                                                   unsigned short* __restrict__ P,
                                                   float* __restrict__ Cpart,
                                                   int* __restrict__ n0part,
                                                   float* __restrict__ scal,
                                                   int* __restrict__ counter) {
    int tid = threadIdx.x, wave = tid >> 6, lane = tid & 63;
    int l15 = lane & 15, lhi = lane >> 4;
    int jtile = blockIdx.x * 4 + wave;
    int row = jtile * 16 + l15;

    float v[4][8];
    float ss = 0.f;
    #pragma unroll
    for (int kb = 0; kb < 4; ++kb) {
        const float4* xp = reinterpret_cast<const float4*>(X + (size_t)row * D_DIM + kb * 32 + lhi * 8);
        float4 a = xp[0], b = xp[1];
        v[kb][0] = a.x; v[kb][1] = a.y; v[kb][2] = a.z; v[kb][3] = a.w;
        v[kb][4] = b.x; v[kb][5] = b.y; v[kb][6] = b.z; v[kb][7] = b.w;
        ss += a.x*a.x + a.y*a.y + a.z*a.z + a.w*a.w
            + b.x*b.x + b.y*b.y + b.z*b.z + b.w*b.w;
    }
    ss += __shfl_xor(ss, 16);
    ss += __shfl_xor(ss, 32);
    float rn = rsqrtf(ss) * SCALE;
    bool is0 = (labels[row] == 0);

    #pragma unroll
    for (int kb = 0; kb < 4; ++kb) {
        u16x8 o;
        #pragma unroll
        for (int e = 0; e < 8; ++e) { v[kb][e] *= rn; o[e] = f2bf(v[kb][e]); }
        *reinterpret_cast<u16x8*>(P + ((size_t)jtile * 4 + kb) * 512 + lane * 8) = o;
    }

    // class column-sums via LDS, then per-block plain store
    __shared__ float CL[256];
    CL[tid] = 0.f;
    __syncthreads();
    int cbase = is0 ? 0 : 128;
    #pragma unroll
    for (int kb = 0; kb < 4; ++kb)
        #pragma unroll
        for (int e = 0; e < 8; ++e)
            atomicAdd(&CL[cbase + kb * 32 + lhi * 8 + e], v[kb][e]);
    __syncthreads();
    Cpart[(size_t)blockIdx.x * 256 + tid] = CL[tid];

    // class-0 count: one lane per row (lhi==0)
    unsigned long long b = __ballot(is0 && lhi == 0);
    if (lane == 0 && wave == 0) {
        // recount across the whole block's 64 rows handled by wave 0? No:
        // each wave counted only its own 16 rows in b. Store per-wave via LDS.
    }
    __shared__ int nred[4];
    if (lane == 0) nred[wave] = (int)__popcll(b);
    __syncthreads();
    if (tid == 0) {
        n0part[blockIdx.x] = nred[0] + nred[1] + nred[2] + nred[3];
        if (blockIdx.x == 0) { scal[0] = 0.f; scal[1] = 0.f; *counter = 0; }
    }
}

// ---------------------------------------------------------------------------
// main: S1part[split][i] = sum_{j in split} exp(sim_ij); split = 256 cols.
// No LDS, no barriers. Wave owns 32 rows (af = 32 VGPR, low pressure so the
// allocator keeps them resident). Depth-4 register pipeline over 16-col tiles
// (named b0..b3, compile-time rotation): 4 tiles of loads in flight cover L2
// latency; all loads are packed fragments (P + f*1024B + lane*16B, coalesced).
__global__ __launch_bounds__(256) void main_kernel(const unsigned short* __restrict__ Pk,
                                                   float* __restrict__ S1part,
                                                   int N) {
    int tid = threadIdx.x, wave = tid >> 6, lane = tid & 63;
    int l15 = lane & 15, lhi = lane >> 4;
    int m0 = blockIdx.x * 128 + wave * 32;
    int split = blockIdx.y;
    const int TILES = 16;                  // 256 cols per split
    int t0 = split * TILES;

    const u16x8* P = reinterpret_cast<const u16x8*>(Pk);

    bf16x8 af[2][4];
    int fa0 = (m0 >> 4) << 2;
    #pragma unroll
    for (int ms = 0; ms < 2; ++ms)
        #pragma unroll
        for (int kb = 0; kb < 4; ++kb)
            af[ms][kb] = __builtin_bit_cast(bf16x8, P[(size_t)(fa0 + ms * 4 + kb) * 64 + lane]);

    float s1[2][4];
    #pragma unroll
    for (int ms = 0; ms < 2; ++ms)
        #pragma unroll
        for (int r = 0; r < 4; ++r) s1[ms][r] = 0.f;

    bf16x8 b0[4], b1[4], b2[4], b3[4];

    auto LOADB = [&](bf16x8* buf, int t) {
        #pragma unroll
        for (int kb = 0; kb < 4; ++kb)
            buf[kb] = __builtin_bit_cast(bf16x8, P[(size_t)((t0 + t) * 4 + kb) * 64 + lane]);
    };
    auto COMP = [&](const bf16x8* buf) {
        f32x4 acc[2] = {{0,0,0,0},{0,0,0,0}};
        #pragma unroll
        for (int kb = 0; kb < 4; ++kb)
            #pragma unroll
            for (int ms = 0; ms < 2; ++ms)
                acc[ms] = __builtin_amdgcn_mfma_f32_16x16x32_bf16(af[ms][kb], buf[kb], acc[ms], 0, 0, 0);
        #pragma unroll
        for (int ms = 0; ms < 2; ++ms)
            #pragma unroll
            for (int r = 0; r < 4; ++r)
                s1[ms][r] += __builtin_amdgcn_exp2f(acc[ms][r]);
    };

    LOADB(b0, 0); LOADB(b1, 1); LOADB(b2, 2);
    #pragma unroll
    for (int t = 0; t < TILES; t += 4) {
        if (t + 3 < TILES) LOADB(b3, t + 3);
        COMP(b0);
        if (t + 4 < TILES) LOADB(b0, t + 4);
        COMP(b1);
        if (t + 5 < TILES) LOADB(b1, t + 5);
        COMP(b2);
        if (t + 6 < TILES) LOADB(b2, t + 6);
        COMP(b3);
    }

    // reduce over the 16 l15-lanes holding the same rows
    #pragma unroll
    for (int m = 1; m < 16; m <<= 1)
        #pragma unroll
        for (int ms = 0; ms < 2; ++ms)
            #pragma unroll
            for (int r = 0; r < 4; ++r)
                s1[ms][r] += __shfl_xor(s1[ms][r], m);
    if (l15 == 0) {
        #pragma unroll
        for (int ms = 0; ms < 2; ++ms)
            #pragma unroll
            for (int r = 0; r < 4; ++r)
                S1part[(size_t)split * N + m0 + ms * 16 + lhi * 4 + r] = s1[ms][r];
    }
}

// ---------------------------------------------------------------------------
// finish: per row S1 = sum of split partials; Lc = sum_{i in c} log(S1_i - e).
// Pos-pair sums via identity: sum_{i in c} sum_{pos j} sim_ij = ||C_c||^2 - n_c.
// Block partials -> scal atomics; last block sums Cpart/n0part + final loss.
__global__ __launch_bounds__(256) void finish_kernel(const float* __restrict__ S1part,
                                                     const float* __restrict__ Cpart,
                                                     const int* __restrict__ labels,
                                                     const int* __restrict__ n0part,
                                                     float* __restrict__ scal,
                                                     int* __restrict__ counter,
                                                     float* __restrict__ out,
                                                     int N, int nsplit, int nprep) {
    int tid = threadIdx.x, wave = tid >> 6, lane = tid & 63;
    int row = blockIdx.x * 256 + tid;

    float S1 = 0.f;
    for (int s = 0; s < nsplit; ++s) S1 += S1part[(size_t)s * N + row];
    bool is0 = (labels[row] == 0);
    float lg = __builtin_amdgcn_logf(S1 - E1F) * LN2;   // natural log of denom
    float v0 = is0 ? lg : 0.f, v1 = is0 ? 0.f : lg;
    #pragma unroll
    for (int m = 1; m < 64; m <<= 1) { v0 += __shfl_xor(v0, m); v1 += __shfl_xor(v1, m); }

    __shared__ float red[4][2];
    __shared__ int isLast;
    if (lane == 0) { red[wave][0] = v0; red[wave][1] = v1; }
    __syncthreads();
    if (tid == 0) {
        atomicAdd(&scal[0], red[0][0] + red[1][0] + red[2][0] + red[3][0]);
        atomicAdd(&scal[1], red[0][1] + red[1][1] + red[2][1] + red[3][1]);
        __threadfence();
        int old = atomicAdd(counter, 1);
        isLast = (old == (int)gridDim.x - 1) ? 1 : 0;
    }
    __syncthreads();
    if (isLast) {
        // column-sum Cpart: tid<128 = class0 columns, tid>=128 = class1
        float csum = 0.f;
        for (int b = 0; b < nprep; ++b) csum += Cpart[(size_t)b * 256 + tid];
        float sq = csum * csum;
        #pragma unroll
        for (int m = 1; m < 64; m <<= 1) sq += __shfl_xor(sq, m);
        int nv = (tid < nprep) ? n0part[tid] : 0;
        #pragma unroll
        for (int m = 1; m < 64; m <<= 1) nv += __shfl_xor(nv, m);

        __shared__ float sqred[4];
        __shared__ int   nred2[4];
        if (lane == 0) { sqred[wave] = sq; nred2[wave] = nv; }
        __syncthreads();
        if (tid == 0) {
            float C0sq = (sqred[0] + sqred[1]) * LN2;   // un-scale: SCALE^2 = log2e
            float C1sq = (sqred[2] + sqred[3]) * LN2;
            int   n0 = nred2[0] + nred2[1] + nred2[2] + nred2[3];
            float L0 = atomicAdd(&scal[0], 0.f);
            float L1 = atomicAdd(&scal[1], 0.f);
            float fn0 = (float)n0, fn1 = (float)(N - n0);
            float P0 = C0sq - fn0, P1 = C1sq - fn1;
            out[0] = ((fn0 - 1.f) * L0 - P0) / fn0 + (fn1 - 1.f) * L1 - P1;
        }
    }
}

// ---------------------------------------------------------------------------
extern "C" void kernel_launch(void* const* d_in, const int* in_sizes, int n_in,
                              void* d_out, int out_size, void* d_ws, size_t ws_size,
                              hipStream_t stream) {
    (void)n_in; (void)out_size; (void)ws_size;
    const float* X      = (const float*)d_in[0];
    const int*   labels = (const int*)d_in[1];
    int N = in_sizes[1];                       // 8192; assumes D=128, N % 256 == 0
    int nprep  = N / 64;                       // 128
    int nsplit = NSPLIT;                       // 32: each split = 256 cols

    char* ws = (char*)d_ws;
    unsigned short* P       = (unsigned short*)ws;                                // 2 MB
    float*          S1part  = (float*)(ws + (size_t)N * D_DIM * 2);               // nsplit*N*4 = 1 MB
    float*          Cpart   = (float*)((char*)S1part + (size_t)nsplit * N * 4);   // nprep*1KB = 128 KB
    int*            n0part  = (int*)((char*)Cpart + (size_t)nprep * 256 * 4);     // 512 B
    float*          scal    = (float*)((char*)n0part + (size_t)nprep * 4);        // 8 B
    int*            counter = (int*)((char*)scal + 8);
    float*          out     = (float*)d_out;

    prep_kernel<<<nprep, 256, 0, stream>>>(X, labels, P, Cpart, n0part, scal, counter);

    dim3 grid(N / 128, nsplit);
    main_kernel<<<grid, 256, 0, stream>>>(P, S1part, N);

    finish_kernel<<<N / 256, 256, 0, stream>>>(S1part, Cpart, labels, n0part, scal, counter, out, N, nsplit, nprep);
}

// Round 10
// 130.403 us; speedup vs baseline: 1.2292x; 1.2292x over previous
//
#include <hip/hip_runtime.h>

typedef float f32x4 __attribute__((ext_vector_type(4)));
typedef __bf16 bf16x8 __attribute__((ext_vector_type(8)));
typedef unsigned short u16x8 __attribute__((ext_vector_type(8)));

#define D_DIM 128
#define NSPLIT 16
#define TILES  8      // 64-col tiles per split: jlen = 8*64 = 512
#define SCALE  1.2011224087864498f   // sqrt(log2(e)): both operands scaled -> acc = log2e * sim
#define LN2    0.6931471805599453f
#define E1F    2.7182818284590452f

// fp32 -> bf16 round-to-nearest-even
static __device__ __forceinline__ unsigned short f2bf(float f) {
    unsigned u = __float_as_uint(f);
    u += 0x7fffu + ((u >> 16) & 1u);
    return (unsigned short)(u >> 16);
}

static __device__ __forceinline__ void gload_lds16(const unsigned short* gsrc, void* lds_dst) {
    auto gp = (const __attribute__((address_space(1))) unsigned int*)gsrc;
    auto lp = (__attribute__((address_space(3))) unsigned int*)(unsigned int)(unsigned long long)lds_dst;
    __builtin_amdgcn_global_load_lds(gp, lp, 16, 0, 0);
}

// ---------------------------------------------------------------------------
// prep: normalize rows (scaled by sqrt(log2e)), store A in MFMA-fragment
// order. Fragment f = jtile*4 + kb is 1 KB: lane l holds row jtile*16+(l&15),
// k = kb*32 + (l>>4)*8 .. +7. Per-block class column-sum partials Cpart
// (plain stores), n0part. Block 0 zeroes scal/counter.
__global__ __launch_bounds__(256) void prep_kernel(const float* __restrict__ X,
                                                   const int* __restrict__ labels,
                                                   unsigned short* __restrict__ P,
                                                   float* __restrict__ Cpart,
                                                   int* __restrict__ n0part,
                                                   float* __restrict__ scal,
                                                   int* __restrict__ counter) {
    int tid = threadIdx.x, wave = tid >> 6, lane = tid & 63;
    int l15 = lane & 15, lhi = lane >> 4;
    int jtile = blockIdx.x * 4 + wave;
    int row = jtile * 16 + l15;

    float v[4][8];
    float ss = 0.f;
    #pragma unroll
    for (int kb = 0; kb < 4; ++kb) {
        const float4* xp = reinterpret_cast<const float4*>(X + (size_t)row * D_DIM + kb * 32 + lhi * 8);
        float4 a = xp[0], b = xp[1];
        v[kb][0] = a.x; v[kb][1] = a.y; v[kb][2] = a.z; v[kb][3] = a.w;
        v[kb][4] = b.x; v[kb][5] = b.y; v[kb][6] = b.z; v[kb][7] = b.w;
        ss += a.x*a.x + a.y*a.y + a.z*a.z + a.w*a.w
            + b.x*b.x + b.y*b.y + b.z*b.z + b.w*b.w;
    }
    ss += __shfl_xor(ss, 16);
    ss += __shfl_xor(ss, 32);
    float rn = rsqrtf(ss) * SCALE;
    bool is0 = (labels[row] == 0);

    #pragma unroll
    for (int kb = 0; kb < 4; ++kb) {
        u16x8 o;
        #pragma unroll
        for (int e = 0; e < 8; ++e) { v[kb][e] *= rn; o[e] = f2bf(v[kb][e]); }
        *reinterpret_cast<u16x8*>(P + ((size_t)jtile * 4 + kb) * 512 + lane * 8) = o;
    }

    // class column-sums via LDS, then per-block plain store
    __shared__ float CL[256];
    CL[tid] = 0.f;
    __syncthreads();
    int cbase = is0 ? 0 : 128;
    #pragma unroll
    for (int kb = 0; kb < 4; ++kb)
        #pragma unroll
        for (int e = 0; e < 8; ++e)
            atomicAdd(&CL[cbase + kb * 32 + lhi * 8 + e], v[kb][e]);
    __syncthreads();
    Cpart[(size_t)blockIdx.x * 256 + tid] = CL[tid];

    // class-0 count: one lane per row (lhi==0), per-wave popcount -> block sum
    unsigned long long b = __ballot(is0 && lhi == 0);
    __shared__ int nred[4];
    if (lane == 0) nred[wave] = (int)__popcll(b);
    __syncthreads();
    if (tid == 0) {
        n0part[blockIdx.x] = nred[0] + nred[1] + nred[2] + nred[3];
        if (blockIdx.x == 0) { scal[0] = 0.f; scal[1] = 0.f; *counter = 0; }
    }
}

// ---------------------------------------------------------------------------
// main: S1part[split][i] = sum_{j in split} exp(sim_ij); split = 512 cols.
// 2-phase double-buffered LDS pipeline (T3 minimal): per 64-col tile (16 KB,
// 16 packed fragments, contiguous in P), STAGE(next) is issued BEFORE the
// compute of the current tile; ONE __syncthreads per tile drains both.
// global_load_lds src and LDS dst are both strictly linear (packed layout);
// ds_read_b128 at lane*16 is conflict-free. Wave owns 64 rows, af resident.
__global__ __launch_bounds__(256) void main_kernel(const unsigned short* __restrict__ Pk,
                                                   float* __restrict__ S1part,
                                                   int N) {
    __shared__ unsigned short Bs[2][8192];    // 2 x 16 KB
    int tid = threadIdx.x, wave = tid >> 6, lane = tid & 63;
    int l15 = lane & 15, lhi = lane >> 4;
    int m0 = blockIdx.x * 256 + wave * 64;
    int split = blockIdx.y;
    int T0 = split * TILES;                    // global 64-col tile index base

    auto stage = [&](int buf, int T) {
        const unsigned short* src = Pk + (size_t)T * 8192 + tid * 8;   // T*16384B + tid*16B
        #pragma unroll
        for (int it = 0; it < 4; ++it)
            gload_lds16(src + it * 2048,
                        (char*)(&Bs[0][0]) + buf * 16384 + it * 4096 + wave * 1024);
    };

    stage(0, T0);

    // A fragments from global — latency hides under the staging barrier
    const u16x8* P = reinterpret_cast<const u16x8*>(Pk);
    int fa0 = (m0 >> 4) << 2;
    bf16x8 af[4][4];
    #pragma unroll
    for (int ms = 0; ms < 4; ++ms)
        #pragma unroll
        for (int kb = 0; kb < 4; ++kb)
            af[ms][kb] = __builtin_bit_cast(bf16x8, P[(size_t)(fa0 + ms * 4 + kb) * 64 + lane]);

    float s1[4][4];
    #pragma unroll
    for (int ms = 0; ms < 4; ++ms)
        #pragma unroll
        for (int r = 0; r < 4; ++r) s1[ms][r] = 0.f;

    __syncthreads();

    int buf = 0;
    #pragma unroll
    for (int t = 0; t < TILES; ++t) {
        if (t + 1 < TILES) stage(buf ^ 1, T0 + t + 1);   // prefetch next tile
        const char* BsB = (const char*)(&Bs[0][0]) + buf * 16384;
        #pragma unroll
        for (int cs = 0; cs < 4; ++cs) {
            bf16x8 bf[4];
            #pragma unroll
            for (int kb = 0; kb < 4; ++kb)
                bf[kb] = *reinterpret_cast<const bf16x8*>(BsB + (cs * 4 + kb) * 1024 + lane * 16);
            f32x4 acc[4] = {{0,0,0,0},{0,0,0,0},{0,0,0,0},{0,0,0,0}};
            #pragma unroll
            for (int kb = 0; kb < 4; ++kb)
                #pragma unroll
                for (int ms = 0; ms < 4; ++ms)
                    acc[ms] = __builtin_amdgcn_mfma_f32_16x16x32_bf16(af[ms][kb], bf[kb], acc[ms], 0, 0, 0);
            #pragma unroll
            for (int ms = 0; ms < 4; ++ms)
                #pragma unroll
                for (int r = 0; r < 4; ++r)
                    s1[ms][r] += __builtin_amdgcn_exp2f(acc[ms][r]);
        }
        __syncthreads();   // all waves done reading buf; prefetch vmcnt drained
        buf ^= 1;
    }

    // reduce over the 16 l15-lanes holding the same rows
    #pragma unroll
    for (int m = 1; m < 16; m <<= 1)
        #pragma unroll
        for (int ms = 0; ms < 4; ++ms)
            #pragma unroll
            for (int r = 0; r < 4; ++r)
                s1[ms][r] += __shfl_xor(s1[ms][r], m);
    if (l15 == 0) {
        #pragma unroll
        for (int ms = 0; ms < 4; ++ms)
            #pragma unroll
            for (int r = 0; r < 4; ++r)
                S1part[(size_t)split * N + m0 + ms * 16 + lhi * 4 + r] = s1[ms][r];
    }
}

// ---------------------------------------------------------------------------
// finish: per row S1 = sum of split partials; Lc = sum_{i in c} log(S1_i - e).
// Pos-pair sums via identity: sum_{i in c} sum_{pos j} sim_ij = ||C_c||^2 - n_c.
// Block partials -> scal atomics; last block sums Cpart/n0part + final loss.
__global__ __launch_bounds__(256) void finish_kernel(const float* __restrict__ S1part,
                                                     const float* __restrict__ Cpart,
                                                     const int* __restrict__ labels,
                                                     const int* __restrict__ n0part,
                                                     float* __restrict__ scal,
                                                     int* __restrict__ counter,
                                                     float* __restrict__ out,
                                                     int N, int nsplit, int nprep) {
    int tid = threadIdx.x, wave = tid >> 6, lane = tid & 63;
    int row = blockIdx.x * 256 + tid;

    float S1 = 0.f;
    for (int s = 0; s < nsplit; ++s) S1 += S1part[(size_t)s * N + row];
    bool is0 = (labels[row] == 0);
    float lg = __builtin_amdgcn_logf(S1 - E1F) * LN2;   // natural log of denom
    float v0 = is0 ? lg : 0.f, v1 = is0 ? 0.f : lg;
    #pragma unroll
    for (int m = 1; m < 64; m <<= 1) { v0 += __shfl_xor(v0, m); v1 += __shfl_xor(v1, m); }

    __shared__ float red[4][2];
    __shared__ int isLast;
    if (lane == 0) { red[wave][0] = v0; red[wave][1] = v1; }
    __syncthreads();
    if (tid == 0) {
        atomicAdd(&scal[0], red[0][0] + red[1][0] + red[2][0] + red[3][0]);
        atomicAdd(&scal[1], red[0][1] + red[1][1] + red[2][1] + red[3][1]);
        __threadfence();
        int old = atomicAdd(counter, 1);
        isLast = (old == (int)gridDim.x - 1) ? 1 : 0;
    }
    __syncthreads();
    if (isLast) {
        // column-sum Cpart: tid<128 = class0 columns, tid>=128 = class1
        float csum = 0.f;
        for (int b = 0; b < nprep; ++b) csum += Cpart[(size_t)b * 256 + tid];
        float sq = csum * csum;
        #pragma unroll
        for (int m = 1; m < 64; m <<= 1) sq += __shfl_xor(sq, m);
        int nv = (tid < nprep) ? n0part[tid] : 0;
        #pragma unroll
        for (int m = 1; m < 64; m <<= 1) nv += __shfl_xor(nv, m);

        __shared__ float sqred[4];
        __shared__ int   nred2[4];
        if (lane == 0) { sqred[wave] = sq; nred2[wave] = nv; }
        __syncthreads();
        if (tid == 0) {
            float C0sq = (sqred[0] + sqred[1]) * LN2;   // un-scale: SCALE^2 = log2e
            float C1sq = (sqred[2] + sqred[3]) * LN2;
            int   n0 = nred2[0] + nred2[1] + nred2[2] + nred2[3];
            float L0 = atomicAdd(&scal[0], 0.f);
            float L1 = atomicAdd(&scal[1], 0.f);
            float fn0 = (float)n0, fn1 = (float)(N - n0);
            float P0 = C0sq - fn0, P1 = C1sq - fn1;
            out[0] = ((fn0 - 1.f) * L0 - P0) / fn0 + (fn1 - 1.f) * L1 - P1;
        }
    }
}

// ---------------------------------------------------------------------------
extern "C" void kernel_launch(void* const* d_in, const int* in_sizes, int n_in,
                              void* d_out, int out_size, void* d_ws, size_t ws_size,
                              hipStream_t stream) {
    (void)n_in; (void)out_size; (void)ws_size;
    const float* X      = (const float*)d_in[0];
    const int*   labels = (const int*)d_in[1];
    int N = in_sizes[1];                       // 8192; assumes D=128, N % 256 == 0
    int nprep  = N / 64;                       // 128
    int nsplit = NSPLIT;                       // 16: each split = 512 cols

    char* ws = (char*)d_ws;
    unsigned short* P       = (unsigned short*)ws;                                // 2 MB
    float*          S1part  = (float*)(ws + (size_t)N * D_DIM * 2);               // nsplit*N*4 = 512 KB
    float*          Cpart   = (float*)((char*)S1part + (size_t)nsplit * N * 4);   // nprep*1KB = 128 KB
    int*            n0part  = (int*)((char*)Cpart + (size_t)nprep * 256 * 4);     // 512 B
    float*          scal    = (float*)((char*)n0part + (size_t)nprep * 4);        // 8 B
    int*            counter = (int*)((char*)scal + 8);
    float*          out     = (float*)d_out;

    prep_kernel<<<nprep, 256, 0, stream>>>(X, labels, P, Cpart, n0part, scal, counter);

    dim3 grid(N / 256, nsplit);
    main_kernel<<<grid, 256, 0, stream>>>(P, S1part, N);

    finish_kernel<<<N / 256, 256, 0, stream>>>(S1part, Cpart, labels, n0part, scal, counter, out, N, nsplit, nprep);
}